// Round 5
// baseline (661.151 us; speedup 1.0000x reference)
//
#include <hip/hip_runtime.h>
#include <math.h>

#define BATCH  4
#define SEQL   4096
#define DMODEL 1024
#define NSTATE 64
#define LN_EPS 1e-5f
#define NCH    64
#define TCH    64          // SEQL / NCH
#define TB     8           // time sub-block in registers

typedef unsigned short u16;

__device__ __forceinline__ u16 f2bf(float x) {
    unsigned int b = __float_as_uint(x);
    b += 0x7FFF + ((b >> 16) & 1);       // round-to-nearest-even
    return (u16)(b >> 16);
}
__device__ __forceinline__ float bf2f(u16 h) {
    return __uint_as_float(((unsigned int)h) << 16);
}

// ---------------------------------------------------------------------------
// k_ct: C[d][n] (f32) -> CT packed bf16 [n/4][d][4]  (one-time, 256 KB read)
// ---------------------------------------------------------------------------
__global__ __launch_bounds__(256) void k_ct(const float* __restrict__ C,
                                            u16* __restrict__ CT) {
    const int idx = blockIdx.x * 256 + threadIdx.x;      // over N*D = 65536
    const int n = idx >> 10, d = idx & (DMODEL - 1);
    CT[((size_t)(n >> 2) * DMODEL + d) * 4 + (n & 3)] = f2bf(C[(size_t)d * NSTATE + n]);
}

// ---------------------------------------------------------------------------
// k_local: per-(b, d, chunk) local scan, ZERO init, finals only (bf16).
//   f[b][j][n][d] = local final state of chunk j
// ---------------------------------------------------------------------------
__global__ __launch_bounds__(256) void k_local(const float* __restrict__ u,
                                               const float* __restrict__ A_log,
                                               const float* __restrict__ delta,
                                               u16* __restrict__ f) {
    __shared__ __align__(16) float r_lds[NSTATE];
    const int tid = threadIdx.x;
    const int wave = tid >> 6, lane = tid & 63;
    const int b   = blockIdx.x >> 8;            // 16 dtiles * 16 jgroups
    const int rem = blockIdx.x & 255;
    const int dt  = rem >> 4;
    const int jg  = rem & 15;
    const int j   = (jg << 2) | wave;
    const int d   = (dt << 6) | lane;

    if (tid < NSTATE) {
        float A = -expf(A_log[tid]);
        r_lds[tid] = expf(delta[0] * A);
    }
    __syncthreads();

    float s[NSTATE];
#pragma unroll
    for (int n = 0; n < NSTATE; ++n) s[n] = 0.f;

    const float* ub = u + ((size_t)b * SEQL + (size_t)j * TCH) * DMODEL + d;
    for (int tb = 0; tb < TCH / TB; ++tb) {
        float ur[TB];
#pragma unroll
        for (int t = 0; t < TB; ++t)
            ur[t] = ub[(size_t)(tb * TB + t) * DMODEL];
#pragma unroll
        for (int n0 = 0; n0 < NSTATE; n0 += 4) {
            const float4 r4 = *(const float4*)&r_lds[n0];
            float s0 = s[n0], s1 = s[n0 + 1], s2 = s[n0 + 2], s3 = s[n0 + 3];
#pragma unroll
            for (int t = 0; t < TB; ++t) {
                const float ut = ur[t];
                s0 = fmaf(r4.x, s0, ut);
                s1 = fmaf(r4.y, s1, ut);
                s2 = fmaf(r4.z, s2, ut);
                s3 = fmaf(r4.w, s3, ut);
            }
            s[n0] = s0; s[n0 + 1] = s1; s[n0 + 2] = s2; s[n0 + 3] = s3;
        }
    }
    u16* fb = f + (((size_t)b * NCH + j) * NSTATE) * DMODEL + d;
#pragma unroll
    for (int n = 0; n < NSTATE; ++n) fb[(size_t)n * DMODEL] = f2bf(s[n]);
}

// ---------------------------------------------------------------------------
// k_pass2: in-place boundary scan. f[b][j][n][d] (local finals, bf16) becomes
// I[b][j][n][d] = state ENTERING chunk j (bf16). One thread per (b,n,d).
// ---------------------------------------------------------------------------
__global__ __launch_bounds__(256) void k_pass2(const float* __restrict__ A_log,
                                               const float* __restrict__ delta,
                                               u16* __restrict__ f) {
    const int tid = blockIdx.x * 256 + threadIdx.x;  // over B*N*D
    const int d = tid & (DMODEL - 1);
    const int n = (tid >> 10) & (NSTATE - 1);
    const int b = tid >> 16;
    const float A  = -expf(A_log[n]);
    const float rT = expf((float)TCH * delta[0] * A);
    float I = 0.f;
    u16* p = f + ((size_t)b * NCH * NSTATE + n) * DMODEL + d;
    const size_t stride = (size_t)NSTATE * DMODEL;
    for (int j = 0; j < NCH; ++j) {
        float tmp = bf2f(p[(size_t)j * stride]);
        p[(size_t)j * stride] = f2bf(I);
        I = fmaf(rT, I, tmp);
    }
}

// ---------------------------------------------------------------------------
// k_replay_ln: one 1024-thread block per (b, chunk j); thread owns channel d.
// Replays the scan with initial state I, computes
//   y[t,d] = sum_n C[d,n] s[n,t,d] + D[d] u[t,d]
//   z = freq_align[d]*y + (t==0 ? reward[d] : 0)
//   out = LayerNorm_d(z)*gamma + beta
// LN is in-block (block spans all 1024 d). C staged in LDS (packed bf16).
// ---------------------------------------------------------------------------
__global__ __launch_bounds__(1024) void k_replay_ln(const float* __restrict__ u,
                                                    const float* __restrict__ A_log,
                                                    const u16* __restrict__ CT,
                                                    const float* __restrict__ Dvec,
                                                    const float* __restrict__ delta,
                                                    const u16* __restrict__ I,
                                                    const float* __restrict__ gamma,
                                                    const float* __restrict__ beta,
                                                    const float* __restrict__ fal,
                                                    const float* __restrict__ rw,
                                                    float* __restrict__ y) {
    __shared__ __align__(16) u16  c_lds[NSTATE * DMODEL];   // packed [n/4][d][4], 128 KB
    __shared__ __align__(16) float r_lds[NSTATE];
    __shared__ float red[TB * 16 * 2];   // [t][wave][{sum,sq}]
    __shared__ float fin[TB * 2];        // [t][{sum,sq}]

    const int tid  = threadIdx.x;
    const int wave = tid >> 6, lane = tid & 63;
    const int b = blockIdx.x >> 6;
    const int j = blockIdx.x & (NCH - 1);

    {   // stage C (b128 copies, coalesced, conflict-free)
        const uint4* src = (const uint4*)CT;
        uint4* dst = (uint4*)c_lds;
#pragma unroll
        for (int k = tid; k < NSTATE * DMODEL / 8; k += 1024) dst[k] = src[k];
    }
    if (tid < NSTATE) {
        float A = -expf(A_log[tid]);
        r_lds[tid] = expf(delta[0] * A);
    }
    __syncthreads();

    const int d = tid;
    float s[NSTATE];
    const u16* Ib = I + (((size_t)b * NCH + j) * NSTATE) * DMODEL + d;
#pragma unroll
    for (int n = 0; n < NSTATE; ++n) s[n] = bf2f(Ib[(size_t)n * DMODEL]);

    const float Dd = Dvec[d], fad = fal[d], gd = gamma[d], bd = beta[d], rwd = rw[d];
    const float* ub = u + ((size_t)b * SEQL + (size_t)j * TCH) * DMODEL + d;
    float*       yb = y + ((size_t)b * SEQL + (size_t)j * TCH) * DMODEL + d;

    for (int tb = 0; tb < TCH / TB; ++tb) {
        float ur[TB], z[TB];
#pragma unroll
        for (int t = 0; t < TB; ++t) {
            ur[t] = ub[(size_t)(tb * TB + t) * DMODEL];
            z[t] = 0.f;
        }
#pragma unroll
        for (int n0 = 0; n0 < NSTATE; n0 += 4) {
            const float4 r4 = *(const float4*)&r_lds[n0];
            const ushort4 cv = *(const ushort4*)&c_lds[((size_t)(n0 >> 2) * DMODEL + d) * 4];
            const float c0 = bf2f(cv.x), c1 = bf2f(cv.y), c2 = bf2f(cv.z), c3 = bf2f(cv.w);
            float s0 = s[n0], s1 = s[n0 + 1], s2 = s[n0 + 2], s3 = s[n0 + 3];
#pragma unroll
            for (int t = 0; t < TB; ++t) {
                const float ut = ur[t];
                s0 = fmaf(r4.x, s0, ut);
                s1 = fmaf(r4.y, s1, ut);
                s2 = fmaf(r4.z, s2, ut);
                s3 = fmaf(r4.w, s3, ut);
                float a = fmaf(c0, s0, z[t]);
                a = fmaf(c1, s1, a);
                a = fmaf(c2, s2, a);
                z[t] = fmaf(c3, s3, a);
            }
            s[n0] = s0; s[n0 + 1] = s1; s[n0 + 2] = s2; s[n0 + 3] = s3;
        }
        // finalize z: skip-connection, spectrum scale, reward impulse
#pragma unroll
        for (int t = 0; t < TB; ++t)
            z[t] = fad * fmaf(Dd, ur[t], z[t]);
        if (j == 0 && tb == 0) z[0] += rwd;

        // per-row block-wide LN reduction
#pragma unroll
        for (int t = 0; t < TB; ++t) {
            float sv = z[t], qv = z[t] * z[t];
#pragma unroll
            for (int off = 32; off > 0; off >>= 1) {
                sv += __shfl_down(sv, off, 64);
                qv += __shfl_down(qv, off, 64);
            }
            if (lane == 0) {
                red[t * 32 + wave * 2]     = sv;
                red[t * 32 + wave * 2 + 1] = qv;
            }
        }
        __syncthreads();
        if (wave < TB && lane < 32) {        // wave t reduces row t's 16 partials
            float v = red[wave * 32 + lane];
            v += __shfl_xor(v, 2, 64);
            v += __shfl_xor(v, 4, 64);
            v += __shfl_xor(v, 8, 64);
            v += __shfl_xor(v, 16, 64);
            if (lane < 2) fin[wave * 2 + lane] = v;
        }
        __syncthreads();
#pragma unroll
        for (int t = 0; t < TB; ++t) {
            const float mean = fin[t * 2] * (1.f / DMODEL);
            const float var  = fin[t * 2 + 1] * (1.f / DMODEL) - mean * mean;
            const float inv  = 1.f / sqrtf(var + LN_EPS);
            yb[(size_t)(tb * TB + t) * DMODEL] = (z[t] - mean) * inv * gd + bd;
        }
    }
}

// ---------------------------------------------------------------------------
// k_state: final_state[b,n] = ((exp(dmean*A_n)-1)/A_safe_n) *
//                             sum_d B[n,d] * u[b, L-1, d]
// ---------------------------------------------------------------------------
__global__ __launch_bounds__(256) void k_state(const float* __restrict__ u,
                                               const float* __restrict__ A_log,
                                               const float* __restrict__ B,
                                               const float* __restrict__ delta,
                                               float* __restrict__ out) {
    const int n = blockIdx.x & 63;
    const int b = blockIdx.x >> 6;
    const int tid = threadIdx.x;
    const float* ul = u + ((size_t)b * SEQL + (SEQL - 1)) * DMODEL;
    const float* Bn = B + (size_t)n * DMODEL;
    float dot = 0.f, dsum = 0.f;
    for (int dd = tid; dd < DMODEL; dd += 256) {
        dot = fmaf(Bn[dd], ul[dd], dot);
        dsum += delta[dd];
    }
#pragma unroll
    for (int off = 32; off > 0; off >>= 1) {
        dot  += __shfl_down(dot,  off, 64);
        dsum += __shfl_down(dsum, off, 64);
    }
    __shared__ float red[8];
    const int wave = tid >> 6, lane = tid & 63;
    if (lane == 0) { red[wave] = dot; red[4 + wave] = dsum; }
    __syncthreads();
    if (tid == 0) {
        dot  = red[0] + red[1] + red[2] + red[3];
        dsum = red[4] + red[5] + red[6] + red[7];
        const float dmean = dsum * (1.f / DMODEL);
        const float A = -expf(A_log[n]);
        const float Abar = expf(dmean * A);
        const float Asafe = A + (A >= 0.f ? 1e-8f : -1e-8f);
        out[blockIdx.x] = ((Abar - 1.f) / Asafe) * dot;
    }
}

extern "C" void kernel_launch(void* const* d_in, const int* in_sizes, int n_in,
                              void* d_out, int out_size, void* d_ws, size_t ws_size,
                              hipStream_t stream) {
    const float* u     = (const float*)d_in[0];
    const float* A_log = (const float*)d_in[1];
    const float* B     = (const float*)d_in[2];
    const float* C     = (const float*)d_in[3];
    const float* Dv    = (const float*)d_in[4];
    const float* delta = (const float*)d_in[5];
    const float* gamma = (const float*)d_in[6];
    const float* beta  = (const float*)d_in[7];
    const float* fal   = (const float*)d_in[8];
    const float* rw    = (const float*)d_in[9];

    float* y  = (float*)d_out;
    float* st = y + (size_t)BATCH * SEQL * DMODEL;

    u16* f  = (u16*)d_ws;                                         // 32 MB
    u16* CT = (u16*)((char*)d_ws + (size_t)BATCH * NCH * NSTATE * DMODEL * sizeof(u16));

    hipLaunchKernelGGL(k_ct, dim3(NSTATE * DMODEL / 256), dim3(256), 0, stream, C, CT);
    hipLaunchKernelGGL(k_local, dim3(BATCH * 16 * (NCH / 4)), dim3(256), 0, stream,
                       u, A_log, delta, f);
    hipLaunchKernelGGL(k_pass2, dim3(BATCH * NSTATE * DMODEL / 256), dim3(256), 0, stream,
                       A_log, delta, f);
    hipLaunchKernelGGL(k_replay_ln, dim3(BATCH * NCH), dim3(1024), 0, stream,
                       u, A_log, CT, Dv, delta, f, gamma, beta, fal, rw, y);
    hipLaunchKernelGGL(k_state, dim3(BATCH * NSTATE), dim3(256), 0, stream,
                       u, A_log, B, delta, st);
}

// Round 6
// 135.535 us; speedup vs baseline: 4.8781x; 4.8781x over previous
//
#include <hip/hip_runtime.h>
#include <math.h>

#define BATCH  4
#define SEQL   4096
#define DMODEL 1024
#define NSTATE 64
#define LN_EPS 1e-5f
#define TB     8           // time rows staged/processed per iteration

typedef unsigned short u16;

__device__ __forceinline__ u16 f2bf(float x) {
    unsigned int b = __float_as_uint(x);
    b += 0x7FFF + ((b >> 16) & 1);       // round-to-nearest-even
    return (u16)(b >> 16);
}
__device__ __forceinline__ float bf2f(u16 h) {
    return __uint_as_float(((unsigned int)h) << 16);
}

// ---------------------------------------------------------------------------
// k_local: block = (b, d-tile 64, chunk j). 4 waves; wave w owns states
// n in [16w, 16w+16); lane = d. Local scan with ZERO init; writes bf16 finals
//   f[b][j][n][d].   Per-thread state = 16 floats (NO spill).
// ---------------------------------------------------------------------------
__global__ __launch_bounds__(256) void k_local(const float* __restrict__ u,
                                               const float* __restrict__ A_log,
                                               const float* __restrict__ delta,
                                               u16* __restrict__ f,
                                               int NCH, int TCH) {
    __shared__ float r_lds[NSTATE];
    __shared__ float u_tile[TB][64];
    const int tid = threadIdx.x;
    const int w = tid >> 6, l = tid & 63;
    const int b   = blockIdx.x / (16 * NCH);
    const int rem = blockIdx.x % (16 * NCH);
    const int dt  = rem / NCH;
    const int j   = rem % NCH;
    const int n0  = w << 4;
    const int d   = (dt << 6) | l;

    if (tid < NSTATE) r_lds[tid] = expf(delta[0] * -expf(A_log[tid]));
    __syncthreads();

    float r_[16];
#pragma unroll
    for (int q = 0; q < 4; ++q)
        *(float4*)&r_[q * 4] = *(const float4*)&r_lds[n0 + q * 4];

    float s_[16];
#pragma unroll
    for (int i = 0; i < 16; ++i) s_[i] = 0.f;

    const float* ubase = u + ((size_t)b * SEQL + (size_t)j * TCH) * DMODEL + (dt << 6);
    const int sr = tid >> 6, sc = tid & 63;          // staging row/col
    for (int tb = 0; tb < TCH / TB; ++tb) {
        u_tile[sr][sc]     = ubase[(size_t)(tb * TB + sr) * DMODEL + sc];
        u_tile[sr + 4][sc] = ubase[(size_t)(tb * TB + sr + 4) * DMODEL + sc];
        __syncthreads();
        float ur[TB];
#pragma unroll
        for (int t = 0; t < TB; ++t) ur[t] = u_tile[t][l];
#pragma unroll
        for (int q = 0; q < 4; ++q) {
            float s0 = s_[q*4], s1 = s_[q*4+1], s2 = s_[q*4+2], s3 = s_[q*4+3];
            const float r0 = r_[q*4], r1 = r_[q*4+1], r2 = r_[q*4+2], r3 = r_[q*4+3];
#pragma unroll
            for (int t = 0; t < TB; ++t) {
                const float ut = ur[t];
                s0 = fmaf(r0, s0, ut);
                s1 = fmaf(r1, s1, ut);
                s2 = fmaf(r2, s2, ut);
                s3 = fmaf(r3, s3, ut);
            }
            s_[q*4] = s0; s_[q*4+1] = s1; s_[q*4+2] = s2; s_[q*4+3] = s3;
        }
        __syncthreads();                              // u_tile reuse guard
    }
    u16* fb = f + (((size_t)b * NCH + j) * NSTATE + n0) * DMODEL + d;
#pragma unroll
    for (int i = 0; i < 16; ++i) fb[(size_t)i * DMODEL] = f2bf(s_[i]);
}

// ---------------------------------------------------------------------------
// k_pass2: in-place boundary scan (bf16). f[b][j][n][d] (local finals) ->
// I[b][j][n][d] = state ENTERING chunk j. One thread per (b,n,d).
// ---------------------------------------------------------------------------
__global__ __launch_bounds__(256) void k_pass2(const float* __restrict__ A_log,
                                               const float* __restrict__ delta,
                                               u16* __restrict__ f,
                                               int NCH, int TCH) {
    const int tid = blockIdx.x * 256 + threadIdx.x;  // over B*N*D
    const int d = tid & (DMODEL - 1);
    const int n = (tid >> 10) & (NSTATE - 1);
    const int b = tid >> 16;
    const float A  = -expf(A_log[n]);
    const float rT = expf((float)TCH * delta[0] * A);
    float I = 0.f;
    u16* p = f + ((size_t)b * NCH * NSTATE + n) * DMODEL + d;
    const size_t stride = (size_t)NSTATE * DMODEL;
    for (int j = 0; j < NCH; ++j) {
        float tmp = bf2f(p[(size_t)j * stride]);
        p[(size_t)j * stride] = f2bf(I);
        I = fmaf(rT, I, tmp);
    }
}

// ---------------------------------------------------------------------------
// k_replay: block = (b, d-tile 64, chunk j); wave-n-split like k_local.
// Replays scan with initial state I; emits
//   z[t,d] = fal[d] * ( sum_n C[d,n] s[n,t,d] + D[d] u[t,d] ) + reward[d]*(t==0)
// Partial-n contributions reduced via LDS.
// ---------------------------------------------------------------------------
__global__ __launch_bounds__(256) void k_replay(const float* __restrict__ u,
                                                const float* __restrict__ A_log,
                                                const float* __restrict__ C,
                                                const float* __restrict__ Dvec,
                                                const float* __restrict__ delta,
                                                const u16* __restrict__ I,
                                                const float* __restrict__ fal,
                                                const float* __restrict__ rw,
                                                float* __restrict__ z,
                                                int NCH, int TCH) {
    __shared__ float r_lds[NSTATE];
    __shared__ float u_tile[TB][64];
    __shared__ float part[4][TB][64];
    const int tid = threadIdx.x;
    const int w = tid >> 6, l = tid & 63;
    const int b   = blockIdx.x / (16 * NCH);
    const int rem = blockIdx.x % (16 * NCH);
    const int dt  = rem / NCH;
    const int j   = rem % NCH;
    const int n0  = w << 4;
    const int d   = (dt << 6) | l;

    if (tid < NSTATE) r_lds[tid] = expf(delta[0] * -expf(A_log[tid]));
    __syncthreads();

    float r_[16], c_[16], s_[16];
#pragma unroll
    for (int q = 0; q < 4; ++q)
        *(float4*)&r_[q * 4] = *(const float4*)&r_lds[n0 + q * 4];
#pragma unroll
    for (int i = 0; i < 16; ++i)
        c_[i] = C[(size_t)d * NSTATE + n0 + i];       // L2-resident scatter, once
    const u16* Ib = I + (((size_t)b * NCH + j) * NSTATE + n0) * DMODEL + d;
#pragma unroll
    for (int i = 0; i < 16; ++i) s_[i] = bf2f(Ib[(size_t)i * DMODEL]);

    const float Dd = Dvec[d], fad = fal[d], rwd = rw[d];
    const float* ubase = u + ((size_t)b * SEQL + (size_t)j * TCH) * DMODEL + (dt << 6);
    float*       zbase = z + ((size_t)b * SEQL + (size_t)j * TCH) * DMODEL + (dt << 6);

    const int sr = tid >> 6, sc = tid & 63;
    for (int tb = 0; tb < TCH / TB; ++tb) {
        u_tile[sr][sc]     = ubase[(size_t)(tb * TB + sr) * DMODEL + sc];
        u_tile[sr + 4][sc] = ubase[(size_t)(tb * TB + sr + 4) * DMODEL + sc];
        __syncthreads();
        float ur[TB], zr[TB];
#pragma unroll
        for (int t = 0; t < TB; ++t) { ur[t] = u_tile[t][l]; zr[t] = 0.f; }
#pragma unroll
        for (int q = 0; q < 4; ++q) {
            float s0 = s_[q*4], s1 = s_[q*4+1], s2 = s_[q*4+2], s3 = s_[q*4+3];
            const float r0 = r_[q*4], r1 = r_[q*4+1], r2 = r_[q*4+2], r3 = r_[q*4+3];
            const float c0 = c_[q*4], c1 = c_[q*4+1], c2 = c_[q*4+2], c3 = c_[q*4+3];
#pragma unroll
            for (int t = 0; t < TB; ++t) {
                const float ut = ur[t];
                s0 = fmaf(r0, s0, ut);
                s1 = fmaf(r1, s1, ut);
                s2 = fmaf(r2, s2, ut);
                s3 = fmaf(r3, s3, ut);
                float a = fmaf(c0, s0, zr[t]);
                a = fmaf(c1, s1, a);
                a = fmaf(c2, s2, a);
                zr[t] = fmaf(c3, s3, a);
            }
            s_[q*4] = s0; s_[q*4+1] = s1; s_[q*4+2] = s2; s_[q*4+3] = s3;
        }
#pragma unroll
        for (int t = 0; t < TB; ++t) part[w][t][l] = zr[t];
        __syncthreads();
        // wave w finalizes rows 2w, 2w+1
#pragma unroll
        for (int k = 0; k < 2; ++k) {
            const int t = (w << 1) | k;
            float v = (part[0][t][l] + part[1][t][l]) + (part[2][t][l] + part[3][t][l]);
            float zz = fad * fmaf(Dd, u_tile[t][l], v);
            if (j == 0 && tb == 0 && t == 0) zz += rwd;
            zbase[(size_t)(tb * TB + t) * DMODEL + l] = zz;
        }
        __syncthreads();                              // part/u_tile reuse guard
    }
}

// ---------------------------------------------------------------------------
// k_ln: pure in-place LayerNorm over d (fal/reward already applied upstream).
// One 256-thread block per (b,t) row, float4 per thread.
// ---------------------------------------------------------------------------
__global__ __launch_bounds__(256) void k_ln(float* __restrict__ y,
                                            const float* __restrict__ gamma,
                                            const float* __restrict__ beta) {
    const int tid = threadIdx.x;
    float4* row = (float4*)(y + (size_t)blockIdx.x * DMODEL);
    float4 v = row[tid];
    float sum = v.x + v.y + v.z + v.w;
    float sq  = v.x*v.x + v.y*v.y + v.z*v.z + v.w*v.w;
#pragma unroll
    for (int off = 32; off > 0; off >>= 1) {
        sum += __shfl_down(sum, off, 64);
        sq  += __shfl_down(sq,  off, 64);
    }
    __shared__ float red[8];
    const int wave = tid >> 6, lane = tid & 63;
    if (lane == 0) { red[wave] = sum; red[4 + wave] = sq; }
    __syncthreads();
    sum = red[0] + red[1] + red[2] + red[3];
    sq  = red[4] + red[5] + red[6] + red[7];
    const float mean = sum * (1.f / DMODEL);
    const float var  = sq * (1.f / DMODEL) - mean * mean;
    const float inv  = 1.f / sqrtf(var + LN_EPS);
    const float4 g  = ((const float4*)gamma)[tid];
    const float4 bb = ((const float4*)beta)[tid];
    float4 o;
    o.x = (v.x - mean) * inv * g.x + bb.x;
    o.y = (v.y - mean) * inv * g.y + bb.y;
    o.z = (v.z - mean) * inv * g.z + bb.z;
    o.w = (v.w - mean) * inv * g.w + bb.w;
    row[tid] = o;
}

// ---------------------------------------------------------------------------
// k_state: final_state[b,n] = ((exp(dmean*A_n)-1)/A_safe_n) *
//                             sum_d B[n,d] * u[b, L-1, d]
// ---------------------------------------------------------------------------
__global__ __launch_bounds__(256) void k_state(const float* __restrict__ u,
                                               const float* __restrict__ A_log,
                                               const float* __restrict__ B,
                                               const float* __restrict__ delta,
                                               float* __restrict__ out) {
    const int n = blockIdx.x & 63;
    const int b = blockIdx.x >> 6;
    const int tid = threadIdx.x;
    const float* ul = u + ((size_t)b * SEQL + (SEQL - 1)) * DMODEL;
    const float* Bn = B + (size_t)n * DMODEL;
    float dot = 0.f, dsum = 0.f;
    for (int dd = tid; dd < DMODEL; dd += 256) {
        dot = fmaf(Bn[dd], ul[dd], dot);
        dsum += delta[dd];
    }
#pragma unroll
    for (int off = 32; off > 0; off >>= 1) {
        dot  += __shfl_down(dot,  off, 64);
        dsum += __shfl_down(dsum, off, 64);
    }
    __shared__ float red[8];
    const int wave = tid >> 6, lane = tid & 63;
    if (lane == 0) { red[wave] = dot; red[4 + wave] = dsum; }
    __syncthreads();
    if (tid == 0) {
        dot  = red[0] + red[1] + red[2] + red[3];
        dsum = red[4] + red[5] + red[6] + red[7];
        const float dmean = dsum * (1.f / DMODEL);
        const float A = -expf(A_log[n]);
        const float Abar = expf(dmean * A);
        const float Asafe = A + (A >= 0.f ? 1e-8f : -1e-8f);
        out[blockIdx.x] = ((Abar - 1.f) / Asafe) * dot;
    }
}

extern "C" void kernel_launch(void* const* d_in, const int* in_sizes, int n_in,
                              void* d_out, int out_size, void* d_ws, size_t ws_size,
                              hipStream_t stream) {
    const float* u     = (const float*)d_in[0];
    const float* A_log = (const float*)d_in[1];
    const float* B     = (const float*)d_in[2];
    const float* C     = (const float*)d_in[3];
    const float* Dv    = (const float*)d_in[4];
    const float* delta = (const float*)d_in[5];
    const float* gamma = (const float*)d_in[6];
    const float* beta  = (const float*)d_in[7];
    const float* fal   = (const float*)d_in[8];
    const float* rw    = (const float*)d_in[9];

    float* y  = (float*)d_out;
    float* st = y + (size_t)BATCH * SEQL * DMODEL;
    u16* f    = (u16*)d_ws;

    int NCH = 32;
    while (NCH > 4 && (size_t)BATCH * NCH * NSTATE * DMODEL * sizeof(u16) > ws_size)
        NCH >>= 1;
    const int TCH = SEQL / NCH;
    const int nb = BATCH * 16 * NCH;

    hipLaunchKernelGGL(k_local, dim3(nb), dim3(256), 0, stream, u, A_log, delta, f, NCH, TCH);
    hipLaunchKernelGGL(k_pass2, dim3(BATCH * NSTATE * DMODEL / 256), dim3(256), 0, stream,
                       A_log, delta, f, NCH, TCH);
    hipLaunchKernelGGL(k_replay, dim3(nb), dim3(256), 0, stream,
                       u, A_log, C, Dv, delta, f, fal, rw, y, NCH, TCH);
    hipLaunchKernelGGL(k_ln, dim3(BATCH * SEQL), dim3(256), 0, stream, y, gamma, beta);
    hipLaunchKernelGGL(k_state, dim3(BATCH * NSTATE), dim3(256), 0, stream,
                       u, A_log, B, delta, st);
}

// Round 7
// 134.312 us; speedup vs baseline: 4.9225x; 1.0091x over previous
//
#include <hip/hip_runtime.h>
#include <math.h>

#define BATCH  4
#define SEQL   4096
#define DMODEL 1024
#define NSTATE 64
#define LN_EPS 1e-5f
#define TB     16          // time rows processed per iteration

typedef unsigned short u16;

__device__ __forceinline__ u16 f2bf(float x) {
    unsigned int b = __float_as_uint(x);
    b += 0x7FFF + ((b >> 16) & 1);       // round-to-nearest-even
    return (u16)(b >> 16);
}
__device__ __forceinline__ float bf2f(u16 h) {
    return __uint_as_float(((unsigned int)h) << 16);
}

// ---------------------------------------------------------------------------
// k_local: block = (b, d-tile 64, chunk j). 4 waves; wave w owns states
// n in [16w, 16w+16); lane = d. Local scan with ZERO init; bf16 finals
// f[b][j][n][d]. Direct global u loads (4-wave redundancy is L1-served);
// NO barriers in the main loop.
// ---------------------------------------------------------------------------
__global__ __launch_bounds__(256) void k_local(const float* __restrict__ u,
                                               const float* __restrict__ A_log,
                                               const float* __restrict__ delta,
                                               u16* __restrict__ f,
                                               int NCH, int TCH) {
    __shared__ float r_lds[NSTATE];
    const int tid = threadIdx.x;
    const int w = tid >> 6, l = tid & 63;
    const int b   = blockIdx.x / (16 * NCH);
    const int rem = blockIdx.x % (16 * NCH);
    const int dt  = rem / NCH;
    const int j   = rem % NCH;
    const int n0  = w << 4;
    const int d   = (dt << 6) | l;

    if (tid < NSTATE) r_lds[tid] = expf(delta[0] * -expf(A_log[tid]));
    __syncthreads();

    float r_[16];
#pragma unroll
    for (int q = 0; q < 4; ++q)
        *(float4*)&r_[q * 4] = *(const float4*)&r_lds[n0 + q * 4];

    float s_[16];
#pragma unroll
    for (int i = 0; i < 16; ++i) s_[i] = 0.f;

    const float* ub = u + ((size_t)b * SEQL + (size_t)j * TCH) * DMODEL + d;
    for (int tb = 0; tb < TCH / TB; ++tb) {
        float ur[TB];
#pragma unroll
        for (int t = 0; t < TB; ++t)
            ur[t] = ub[(size_t)(tb * TB + t) * DMODEL];
#pragma unroll
        for (int q = 0; q < 4; ++q) {
            float s0 = s_[q*4], s1 = s_[q*4+1], s2 = s_[q*4+2], s3 = s_[q*4+3];
            const float r0 = r_[q*4], r1 = r_[q*4+1], r2 = r_[q*4+2], r3 = r_[q*4+3];
#pragma unroll
            for (int t = 0; t < TB; ++t) {
                const float ut = ur[t];
                s0 = fmaf(r0, s0, ut);
                s1 = fmaf(r1, s1, ut);
                s2 = fmaf(r2, s2, ut);
                s3 = fmaf(r3, s3, ut);
            }
            s_[q*4] = s0; s_[q*4+1] = s1; s_[q*4+2] = s2; s_[q*4+3] = s3;
        }
    }
    u16* fb = f + (((size_t)b * NCH + j) * NSTATE + n0) * DMODEL + d;
#pragma unroll
    for (int i = 0; i < 16; ++i) fb[(size_t)i * DMODEL] = f2bf(s_[i]);
}

// ---------------------------------------------------------------------------
// k_pass2: in-place boundary scan (bf16). f[b][j][n][d] (local finals) ->
// I[b][j][n][d] = state ENTERING chunk j. One thread per (b,n,d).
// ---------------------------------------------------------------------------
__global__ __launch_bounds__(256) void k_pass2(const float* __restrict__ A_log,
                                               const float* __restrict__ delta,
                                               u16* __restrict__ f,
                                               int NCH, int TCH) {
    const int tid = blockIdx.x * 256 + threadIdx.x;  // over B*N*D
    const int d = tid & (DMODEL - 1);
    const int n = (tid >> 10) & (NSTATE - 1);
    const int b = tid >> 16;
    const float A  = -expf(A_log[n]);
    const float rT = expf((float)TCH * delta[0] * A);
    float I = 0.f;
    u16* p = f + ((size_t)b * NCH * NSTATE + n) * DMODEL + d;
    const size_t stride = (size_t)NSTATE * DMODEL;
    for (int j = 0; j < NCH; ++j) {
        float tmp = bf2f(p[(size_t)j * stride]);
        p[(size_t)j * stride] = f2bf(I);
        I = fmaf(rT, I, tmp);
    }
}

// ---------------------------------------------------------------------------
// k_replay: block = (b, d-tile 64, chunk j); wave w owns n in [16w,16w+16).
// Replays scan with initial state I; emits
//   z[t,d] = fal[d]*( sum_n C[d,n] s[n,t,d] + D[d] u[t,d] ) + reward[d]*(t==0)
// Direct global u loads; partials reduced via LDS once per TB=16 rows.
// ---------------------------------------------------------------------------
__global__ __launch_bounds__(256) void k_replay(const float* __restrict__ u,
                                                const float* __restrict__ A_log,
                                                const float* __restrict__ C,
                                                const float* __restrict__ Dvec,
                                                const float* __restrict__ delta,
                                                const u16* __restrict__ I,
                                                const float* __restrict__ fal,
                                                const float* __restrict__ rw,
                                                float* __restrict__ z,
                                                int NCH, int TCH) {
    __shared__ float r_lds[NSTATE];
    __shared__ float part[4][TB][64];                // 16 KB
    const int tid = threadIdx.x;
    const int w = tid >> 6, l = tid & 63;
    const int b   = blockIdx.x / (16 * NCH);
    const int rem = blockIdx.x % (16 * NCH);
    const int dt  = rem / NCH;
    const int j   = rem % NCH;
    const int n0  = w << 4;
    const int d   = (dt << 6) | l;

    if (tid < NSTATE) r_lds[tid] = expf(delta[0] * -expf(A_log[tid]));
    __syncthreads();

    float r_[16], c_[16], s_[16];
#pragma unroll
    for (int q = 0; q < 4; ++q)
        *(float4*)&r_[q * 4] = *(const float4*)&r_lds[n0 + q * 4];
#pragma unroll
    for (int i = 0; i < 16; ++i)
        c_[i] = C[(size_t)d * NSTATE + n0 + i];       // L2-resident, once
    const u16* Ib = I + (((size_t)b * NCH + j) * NSTATE + n0) * DMODEL + d;
#pragma unroll
    for (int i = 0; i < 16; ++i) s_[i] = bf2f(Ib[(size_t)i * DMODEL]);

    const float Dd = Dvec[d], fad = fal[d], rwd = rw[d];
    const float* ub = u + ((size_t)b * SEQL + (size_t)j * TCH) * DMODEL + d;
    float*       zb = z + ((size_t)b * SEQL + (size_t)j * TCH) * DMODEL + d;

    for (int tb = 0; tb < TCH / TB; ++tb) {
        float ur[TB], zr[TB];
#pragma unroll
        for (int t = 0; t < TB; ++t) {
            ur[t] = ub[(size_t)(tb * TB + t) * DMODEL];
            zr[t] = 0.f;
        }
#pragma unroll
        for (int q = 0; q < 4; ++q) {
            float s0 = s_[q*4], s1 = s_[q*4+1], s2 = s_[q*4+2], s3 = s_[q*4+3];
            const float r0 = r_[q*4], r1 = r_[q*4+1], r2 = r_[q*4+2], r3 = r_[q*4+3];
            const float c0 = c_[q*4], c1 = c_[q*4+1], c2 = c_[q*4+2], c3 = c_[q*4+3];
#pragma unroll
            for (int t = 0; t < TB; ++t) {
                const float ut = ur[t];
                s0 = fmaf(r0, s0, ut);
                s1 = fmaf(r1, s1, ut);
                s2 = fmaf(r2, s2, ut);
                s3 = fmaf(r3, s3, ut);
                float a = fmaf(c0, s0, zr[t]);
                a = fmaf(c1, s1, a);
                a = fmaf(c2, s2, a);
                zr[t] = fmaf(c3, s3, a);
            }
            s_[q*4] = s0; s_[q*4+1] = s1; s_[q*4+2] = s2; s_[q*4+3] = s3;
        }
#pragma unroll
        for (int t = 0; t < TB; ++t) part[w][t][l] = zr[t];
        __syncthreads();
        // wave w finalizes rows [4w, 4w+4); u re-read from global (L1-hot)
        // to avoid runtime-indexed register arrays (scratch trap).
#pragma unroll
        for (int k = 0; k < 4; ++k) {
            const int t = (w << 2) | k;
            const float uf = ub[(size_t)(tb * TB + t) * DMODEL];
            const float v = (part[0][t][l] + part[1][t][l]) +
                            (part[2][t][l] + part[3][t][l]);
            float zz = fad * fmaf(Dd, uf, v);
            if (j == 0 && tb == 0 && t == 0) zz += rwd;
            zb[(size_t)(tb * TB + t) * DMODEL] = zz;
        }
        __syncthreads();                              // part reuse guard
    }
}

// ---------------------------------------------------------------------------
// k_ln: pure in-place LayerNorm over d. One block per (b,t) row.
// ---------------------------------------------------------------------------
__global__ __launch_bounds__(256) void k_ln(float* __restrict__ y,
                                            const float* __restrict__ gamma,
                                            const float* __restrict__ beta) {
    const int tid = threadIdx.x;
    float4* row = (float4*)(y + (size_t)blockIdx.x * DMODEL);
    float4 v = row[tid];
    float sum = v.x + v.y + v.z + v.w;
    float sq  = v.x*v.x + v.y*v.y + v.z*v.z + v.w*v.w;
#pragma unroll
    for (int off = 32; off > 0; off >>= 1) {
        sum += __shfl_down(sum, off, 64);
        sq  += __shfl_down(sq,  off, 64);
    }
    __shared__ float red[8];
    const int wave = tid >> 6, lane = tid & 63;
    if (lane == 0) { red[wave] = sum; red[4 + wave] = sq; }
    __syncthreads();
    sum = red[0] + red[1] + red[2] + red[3];
    sq  = red[4] + red[5] + red[6] + red[7];
    const float mean = sum * (1.f / DMODEL);
    const float var  = sq * (1.f / DMODEL) - mean * mean;
    const float inv  = 1.f / sqrtf(var + LN_EPS);
    const float4 g  = ((const float4*)gamma)[tid];
    const float4 bb = ((const float4*)beta)[tid];
    float4 o;
    o.x = (v.x - mean) * inv * g.x + bb.x;
    o.y = (v.y - mean) * inv * g.y + bb.y;
    o.z = (v.z - mean) * inv * g.z + bb.z;
    o.w = (v.w - mean) * inv * g.w + bb.w;
    row[tid] = o;
}

// ---------------------------------------------------------------------------
// k_state: final_state[b,n] = ((exp(dmean*A_n)-1)/A_safe_n) *
//                             sum_d B[n,d] * u[b, L-1, d]
// ---------------------------------------------------------------------------
__global__ __launch_bounds__(256) void k_state(const float* __restrict__ u,
                                               const float* __restrict__ A_log,
                                               const float* __restrict__ B,
                                               const float* __restrict__ delta,
                                               float* __restrict__ out) {
    const int n = blockIdx.x & 63;
    const int b = blockIdx.x >> 6;
    const int tid = threadIdx.x;
    const float* ul = u + ((size_t)b * SEQL + (SEQL - 1)) * DMODEL;
    const float* Bn = B + (size_t)n * DMODEL;
    float dot = 0.f, dsum = 0.f;
    for (int dd = tid; dd < DMODEL; dd += 256) {
        dot = fmaf(Bn[dd], ul[dd], dot);
        dsum += delta[dd];
    }
#pragma unroll
    for (int off = 32; off > 0; off >>= 1) {
        dot  += __shfl_down(dot,  off, 64);
        dsum += __shfl_down(dsum, off, 64);
    }
    __shared__ float red[8];
    const int wave = tid >> 6, lane = tid & 63;
    if (lane == 0) { red[wave] = dot; red[4 + wave] = dsum; }
    __syncthreads();
    if (tid == 0) {
        dot  = red[0] + red[1] + red[2] + red[3];
        dsum = red[4] + red[5] + red[6] + red[7];
        const float dmean = dsum * (1.f / DMODEL);
        const float A = -expf(A_log[n]);
        const float Abar = expf(dmean * A);
        const float Asafe = A + (A >= 0.f ? 1e-8f : -1e-8f);
        out[blockIdx.x] = ((Abar - 1.f) / Asafe) * dot;
    }
}

extern "C" void kernel_launch(void* const* d_in, const int* in_sizes, int n_in,
                              void* d_out, int out_size, void* d_ws, size_t ws_size,
                              hipStream_t stream) {
    const float* u     = (const float*)d_in[0];
    const float* A_log = (const float*)d_in[1];
    const float* B     = (const float*)d_in[2];
    const float* C     = (const float*)d_in[3];
    const float* Dv    = (const float*)d_in[4];
    const float* delta = (const float*)d_in[5];
    const float* gamma = (const float*)d_in[6];
    const float* beta  = (const float*)d_in[7];
    const float* fal   = (const float*)d_in[8];
    const float* rw    = (const float*)d_in[9];

    float* y  = (float*)d_out;
    float* st = y + (size_t)BATCH * SEQL * DMODEL;
    u16* f    = (u16*)d_ws;

    int NCH = 32;
    while (NCH > 4 && (size_t)BATCH * NCH * NSTATE * DMODEL * sizeof(u16) > ws_size)
        NCH >>= 1;
    const int TCH = SEQL / NCH;
    const int nb = BATCH * 16 * NCH;

    hipLaunchKernelGGL(k_local, dim3(nb), dim3(256), 0, stream, u, A_log, delta, f, NCH, TCH);
    hipLaunchKernelGGL(k_pass2, dim3(BATCH * NSTATE * DMODEL / 256), dim3(256), 0, stream,
                       A_log, delta, f, NCH, TCH);
    hipLaunchKernelGGL(k_replay, dim3(nb), dim3(256), 0, stream,
                       u, A_log, C, Dv, delta, f, fal, rw, y, NCH, TCH);
    hipLaunchKernelGGL(k_ln, dim3(BATCH * SEQL), dim3(256), 0, stream, y, gamma, beta);
    hipLaunchKernelGGL(k_state, dim3(BATCH * NSTATE), dim3(256), 0, stream,
                       u, A_log, B, delta, st);
}